// Round 1
// baseline (1955.783 us; speedup 1.0000x reference)
//
#include <hip/hip_runtime.h>
#include <hip/hip_bf16.h>

// MultiLayerGATv2 on MI355X — Round 1: correctness-first full fp32 pipeline.
//
// Pipeline:
//   h = relu(LN(x @ W_in + b_in))
//   for l in 0..1:
//     xl = h @ Wl[l]; xr = h @ Wr[l]
//     per edge (incl. self-loops): logit = att[l] . leaky_relu(xl[src]+xr[dst], 0.2)
//     segment-softmax over dst (max-shift skipped: shift-invariant, logits O(1))
//     gat = segment_sum(alpha * xl[src]) over dst
//     h (or d_out for last layer) = h + elu(LN(gat))

#define NN 50000
#define EE 800000
#define EP (EE + NN)      // edges + self loops
#define IN_DIM 256
#define HID 128
#define SLOPE 0.2f
#define LN_EPS 1e-5f

// ---------------- input GEMM + LN + ReLU ----------------
// block: 128 threads, 8 node-rows per block. grid = NN/8 (50000 % 8 == 0)
__global__ void gemm_in_ln_relu(const float* __restrict__ x,
                                const float* __restrict__ W,
                                const float* __restrict__ b,
                                const float* __restrict__ g,
                                const float* __restrict__ bb,
                                float* __restrict__ h) {
    __shared__ float xs[8][IN_DIM];
    __shared__ float stats[8][2];
    const int tid = threadIdx.x;
    const size_t node0 = (size_t)blockIdx.x * 8;

    // cooperative load of 8 contiguous x rows (8*256 floats) as float4
    const float4* xv = (const float4*)(x + node0 * IN_DIM);
    float4* xsv = (float4*)&xs[0][0];
    for (int i = tid; i < 8 * IN_DIM / 4; i += 128) xsv[i] = xv[i];
    __syncthreads();

    float acc[8];
#pragma unroll
    for (int r = 0; r < 8; r++) acc[r] = 0.f;
    for (int k = 0; k < IN_DIM; k++) {
        float w = W[k * HID + tid];
#pragma unroll
        for (int r = 0; r < 8; r++) acc[r] += xs[r][k] * w;  // LDS broadcast
    }
    const float bv = b[tid];
#pragma unroll
    for (int r = 0; r < 8; r++) acc[r] += bv;

    // LayerNorm over HID per row
    __syncthreads();
#pragma unroll
    for (int r = 0; r < 8; r++) xs[r][tid] = acc[r];
    __syncthreads();
    if (tid < 8) {
        float s = 0.f, s2 = 0.f;
        for (int k = 0; k < HID; k++) { float v = xs[tid][k]; s += v; s2 += v * v; }
        float mu = s / (float)HID;
        stats[tid][0] = mu;
        stats[tid][1] = rsqrtf(s2 / (float)HID - mu * mu + LN_EPS);
    }
    __syncthreads();
    const float gv = g[tid], bbv = bb[tid];
#pragma unroll
    for (int r = 0; r < 8; r++) {
        float v = (acc[r] - stats[r][0]) * stats[r][1] * gv + bbv;
        h[(node0 + r) * HID + tid] = fmaxf(v, 0.f);
    }
}

// ---------------- dual GEMM: xl = h@Wl, xr = h@Wr ----------------
__global__ void gemm_xlxr(const float* __restrict__ h,
                          const float* __restrict__ Wl,
                          const float* __restrict__ Wr,
                          float* __restrict__ xl,
                          float* __restrict__ xr) {
    __shared__ float hs[8][HID];
    const int tid = threadIdx.x;
    const size_t node0 = (size_t)blockIdx.x * 8;

    const float4* hv = (const float4*)(h + node0 * HID);
    float4* hsv = (float4*)&hs[0][0];
    for (int i = tid; i < 8 * HID / 4; i += 128) hsv[i] = hv[i];
    __syncthreads();

    float aL[8], aR[8];
#pragma unroll
    for (int r = 0; r < 8; r++) { aL[r] = 0.f; aR[r] = 0.f; }
    for (int k = 0; k < HID; k++) {
        float wl = Wl[k * HID + tid];
        float wr = Wr[k * HID + tid];
#pragma unroll
        for (int r = 0; r < 8; r++) { aL[r] += hs[r][k] * wl; aR[r] += hs[r][k] * wr; }
    }
#pragma unroll
    for (int r = 0; r < 8; r++) {
        xl[(node0 + r) * HID + tid] = aL[r];
        xr[(node0 + r) * HID + tid] = aR[r];
    }
}

// ---------------- edge pass 1: logits -> a = exp(logit); z[dst] += a ----------------
// one 64-lane wave per edge; lane covers 2 feature elems (same head);
// per-head 16-lane shfl reduction.
__global__ void edge_pass1(const float* __restrict__ xl,
                           const float* __restrict__ xr,
                           const float* __restrict__ att,
                           const int* __restrict__ ei,
                           float* __restrict__ aw,
                           float* __restrict__ z) {
    const int lane = threadIdx.x & 63;
    const long eid = (long)blockIdx.x * 4 + (threadIdx.x >> 6);
    if (eid >= EP) return;
    int s, d;
    if (eid < EE) { s = ei[eid]; d = ei[EE + eid]; }
    else          { s = d = (int)(eid - EE); }

    const float2 xlv = *(const float2*)(xl + (size_t)s * HID + lane * 2);
    const float2 xrv = *(const float2*)(xr + (size_t)d * HID + lane * 2);
    const float2 atv = *(const float2*)(att + lane * 2);
    float e0 = xlv.x + xrv.x; e0 = e0 > 0.f ? e0 : SLOPE * e0;
    float e1 = xlv.y + xrv.y; e1 = e1 > 0.f ? e1 : SLOPE * e1;
    float v = e0 * atv.x + e1 * atv.y;
    v += __shfl_xor(v, 1);
    v += __shfl_xor(v, 2);
    v += __shfl_xor(v, 4);
    v += __shfl_xor(v, 8);
    if ((lane & 15) == 0) {
        const int head = lane >> 4;
        const float a = expf(v);
        aw[eid * 4 + head] = a;
        atomicAdd(&z[(size_t)d * 4 + head], a);
    }
}

// ---------------- edge pass 2: out[dst] += alpha * xl[src] ----------------
__global__ void edge_pass2(const float* __restrict__ xl,
                           const float* __restrict__ aw,
                           const float* __restrict__ z,
                           const int* __restrict__ ei,
                           float* __restrict__ out) {
    const int lane = threadIdx.x & 63;
    const long eid = (long)blockIdx.x * 4 + (threadIdx.x >> 6);
    if (eid >= EP) return;
    int s, d;
    if (eid < EE) { s = ei[eid]; d = ei[EE + eid]; }
    else          { s = d = (int)(eid - EE); }

    const int head = lane >> 4;
    const float alpha = aw[eid * 4 + head] / z[(size_t)d * 4 + head];
    const float2 xlv = *(const float2*)(xl + (size_t)s * HID + lane * 2);
    atomicAdd(&out[(size_t)d * HID + lane * 2 + 0], xlv.x * alpha);
    atomicAdd(&out[(size_t)d * HID + lane * 2 + 1], xlv.y * alpha);
}

// ---------------- LN + ELU + residual ----------------
// one wave per node, lane holds float2
__global__ void ln_elu_res(const float* __restrict__ o,
                           const float* __restrict__ g,
                           const float* __restrict__ b,
                           const float* __restrict__ h,
                           float* __restrict__ dest) {
    const int lane = threadIdx.x & 63;
    const long node = (long)blockIdx.x * 4 + (threadIdx.x >> 6);
    if (node >= NN) return;
    const float2 v = *(const float2*)(o + (size_t)node * HID + lane * 2);
    float s = v.x + v.y;
    float s2 = v.x * v.x + v.y * v.y;
#pragma unroll
    for (int off = 1; off < 64; off <<= 1) {
        s += __shfl_xor(s, off);
        s2 += __shfl_xor(s2, off);
    }
    const float mu = s / (float)HID;
    const float rstd = rsqrtf(s2 / (float)HID - mu * mu + LN_EPS);
    const float gx = g[lane * 2], gy = g[lane * 2 + 1];
    const float bx = b[lane * 2], by = b[lane * 2 + 1];
    float ox = (v.x - mu) * rstd * gx + bx;
    float oy = (v.y - mu) * rstd * gy + by;
    ox = ox > 0.f ? ox : expm1f(ox);
    oy = oy > 0.f ? oy : expm1f(oy);
    const float2 hv = *(const float2*)(h + (size_t)node * HID + lane * 2);
    float2 res;
    res.x = hv.x + ox;
    res.y = hv.y + oy;
    *(float2*)(dest + (size_t)node * HID + lane * 2) = res;
}

extern "C" void kernel_launch(void* const* d_in, const int* in_sizes, int n_in,
                              void* d_out, int out_size, void* d_ws, size_t ws_size,
                              hipStream_t stream) {
    const float* x      = (const float*)d_in[0];
    const float* W_in   = (const float*)d_in[1];
    const float* b_in   = (const float*)d_in[2];
    const float* ln_in_g = (const float*)d_in[3];
    const float* ln_in_b = (const float*)d_in[4];
    const float* Wl     = (const float*)d_in[5];
    const float* Wr     = (const float*)d_in[6];
    const float* att    = (const float*)d_in[7];
    const float* ln_g   = (const float*)d_in[8];
    const float* ln_b   = (const float*)d_in[9];
    const int*   ei     = (const int*)d_in[10];
    float* out = (float*)d_out;

    // workspace carve-up (floats): h, xl, xr, aw, z, gat
    float* h    = (float*)d_ws;
    float* xl   = h  + (size_t)NN * HID;
    float* xr   = xl + (size_t)NN * HID;
    float* aw   = xr + (size_t)NN * HID;
    float* z    = aw + (size_t)EP * 4;
    float* gat  = z  + (size_t)NN * 4;

    gemm_in_ln_relu<<<NN / 8, 128, 0, stream>>>(x, W_in, b_in, ln_in_g, ln_in_b, h);

    const int eblocks = (EP + 3) / 4;
    for (int l = 0; l < 2; l++) {
        gemm_xlxr<<<NN / 8, 128, 0, stream>>>(h, Wl + (size_t)l * HID * HID,
                                              Wr + (size_t)l * HID * HID, xl, xr);
        hipMemsetAsync(z, 0, (size_t)NN * 4 * sizeof(float), stream);
        hipMemsetAsync(gat, 0, (size_t)NN * HID * sizeof(float), stream);
        edge_pass1<<<eblocks, 256, 0, stream>>>(xl, xr, att + (size_t)l * HID, ei, aw, z);
        edge_pass2<<<eblocks, 256, 0, stream>>>(xl, aw, z, ei, gat);
        ln_elu_res<<<(NN + 3) / 4, 256, 0, stream>>>(gat, ln_g + (size_t)l * HID,
                                                     ln_b + (size_t)l * HID, h,
                                                     (l == 0) ? h : out);
    }
}

// Round 2
// 553.908 us; speedup vs baseline: 3.5309x; 3.5309x over previous
//
#include <hip/hip_runtime.h>
#include <hip/hip_bf16.h>

// MultiLayerGATv2 — Round 2: CSR-by-dst + fully fused gather-GAT (no atomics
// in the hot path), softmax denominator factored out (single pass), LN+ELU+
// residual fused into the gather kernel.

#define NN 50000
#define EE 800000
#define EP (EE + NN)      // edges + self loops
#define IN_DIM 256
#define HID 128
#define SLOPE 0.2f
#define LN_EPS 1e-5f

// ---------------- input GEMM + LN + ReLU ----------------
__global__ void gemm_in_ln_relu(const float* __restrict__ x,
                                const float* __restrict__ W,
                                const float* __restrict__ b,
                                const float* __restrict__ g,
                                const float* __restrict__ bb,
                                float* __restrict__ h) {
    __shared__ float xs[8][IN_DIM];
    __shared__ float stats[8][2];
    const int tid = threadIdx.x;
    const size_t node0 = (size_t)blockIdx.x * 8;

    const float4* xv = (const float4*)(x + node0 * IN_DIM);
    float4* xsv = (float4*)&xs[0][0];
    for (int i = tid; i < 8 * IN_DIM / 4; i += 128) xsv[i] = xv[i];
    __syncthreads();

    float acc[8];
#pragma unroll
    for (int r = 0; r < 8; r++) acc[r] = 0.f;
    for (int k = 0; k < IN_DIM; k++) {
        float w = W[k * HID + tid];
#pragma unroll
        for (int r = 0; r < 8; r++) acc[r] += xs[r][k] * w;
    }
    const float bv = b[tid];
#pragma unroll
    for (int r = 0; r < 8; r++) acc[r] += bv;

    __syncthreads();
#pragma unroll
    for (int r = 0; r < 8; r++) xs[r][tid] = acc[r];
    __syncthreads();
    if (tid < 8) {
        float s = 0.f, s2 = 0.f;
        for (int k = 0; k < HID; k++) { float v = xs[tid][k]; s += v; s2 += v * v; }
        float mu = s / (float)HID;
        stats[tid][0] = mu;
        stats[tid][1] = rsqrtf(s2 / (float)HID - mu * mu + LN_EPS);
    }
    __syncthreads();
    const float gv = g[tid], bbv = bb[tid];
#pragma unroll
    for (int r = 0; r < 8; r++) {
        float v = (acc[r] - stats[r][0]) * stats[r][1] * gv + bbv;
        h[(node0 + r) * HID + tid] = fmaxf(v, 0.f);
    }
}

// ---------------- dual GEMM: xl = h@Wl, xr = h@Wr ----------------
__global__ void gemm_xlxr(const float* __restrict__ h,
                          const float* __restrict__ Wl,
                          const float* __restrict__ Wr,
                          float* __restrict__ xl,
                          float* __restrict__ xr) {
    __shared__ float hs[8][HID];
    const int tid = threadIdx.x;
    const size_t node0 = (size_t)blockIdx.x * 8;

    const float4* hv = (const float4*)(h + node0 * HID);
    float4* hsv = (float4*)&hs[0][0];
    for (int i = tid; i < 8 * HID / 4; i += 128) hsv[i] = hv[i];
    __syncthreads();

    float aL[8], aR[8];
#pragma unroll
    for (int r = 0; r < 8; r++) { aL[r] = 0.f; aR[r] = 0.f; }
    for (int k = 0; k < HID; k++) {
        float wl = Wl[k * HID + tid];
        float wr = Wr[k * HID + tid];
#pragma unroll
        for (int r = 0; r < 8; r++) { aL[r] += hs[r][k] * wl; aR[r] += hs[r][k] * wr; }
    }
#pragma unroll
    for (int r = 0; r < 8; r++) {
        xl[(node0 + r) * HID + tid] = aL[r];
        xr[(node0 + r) * HID + tid] = aR[r];
    }
}

// ---------------- CSR build: histogram / scan / scatter ----------------
__global__ void dst_hist(const int* __restrict__ ei, int* __restrict__ cnt) {
    const long e = (long)blockIdx.x * 256 + threadIdx.x;
    if (e >= EP) return;
    const int d = (e < EE) ? ei[EE + e] : (int)(e - EE);
    atomicAdd(&cnt[d], 1);
}

// single-block exclusive scan of NN counts -> rowptr[0..NN]
__global__ void scan_rowptr(const int* __restrict__ cnt, int* __restrict__ rowptr) {
    __shared__ int buf[1024];
    __shared__ int carry;
    const int tid = threadIdx.x;
    if (tid == 0) carry = 0;
    __syncthreads();
    for (int base = 0; base < NN; base += 1024) {
        const int i = base + tid;
        const int v = (i < NN) ? cnt[i] : 0;
        buf[tid] = v;
        __syncthreads();
        for (int off = 1; off < 1024; off <<= 1) {
            int add = (tid >= off) ? buf[tid - off] : 0;
            __syncthreads();
            buf[tid] += add;
            __syncthreads();
        }
        const int c = carry;
        if (i < NN) rowptr[i] = c + buf[tid] - v;   // exclusive
        __syncthreads();
        if (tid == 1023) carry = c + buf[1023];
        __syncthreads();
    }
    if (tid == 0) rowptr[NN] = carry;   // == EP
}

__global__ void csr_scatter(const int* __restrict__ ei,
                            const int* __restrict__ rowptr,
                            int* __restrict__ fill,
                            int* __restrict__ esrc) {
    const long e = (long)blockIdx.x * 256 + threadIdx.x;
    if (e >= EP) return;
    int s, d;
    if (e < EE) { s = ei[e]; d = ei[EE + e]; }
    else        { s = d = (int)(e - EE); }
    const int pos = atomicAdd(&fill[d], 1);
    esrc[rowptr[d] + pos] = s;
}

// ---------------- fused GAT conv + LN + ELU + residual ----------------
// one 64-lane wave per dst node; lane holds feature elems {2*lane, 2*lane+1}.
// softmax denominator factored out: out = (sum_e a_e * xl[src_e]) / (sum_e a_e)
__global__ void gat_ln(const float* __restrict__ xl,
                       const float* __restrict__ xr,
                       const float* __restrict__ att,
                       const int* __restrict__ rowptr,
                       const int* __restrict__ esrc,
                       const float* __restrict__ g,
                       const float* __restrict__ b,
                       const float* __restrict__ hres,
                       float* __restrict__ dest) {
    const int lane = threadIdx.x & 63;
    const int node = blockIdx.x * 4 + (threadIdx.x >> 6);
    if (node >= NN) return;

    const float2 xrv = *(const float2*)(xr + (size_t)node * HID + lane * 2);
    const float2 atv = *(const float2*)(att + lane * 2);
    const int beg = rowptr[node];
    const int deg = rowptr[node + 1] - beg;   // >= 1 (self loop)

    float2 acc; acc.x = 0.f; acc.y = 0.f;
    float z = 0.f;
    int snext = esrc[beg];
    for (int i = 0; i < deg; i++) {
        const int s = snext;
        if (i + 1 < deg) snext = esrc[beg + i + 1];   // prefetch: break dep chain
        const float2 xlv = *(const float2*)(xl + (size_t)s * HID + lane * 2);
        float e0 = xlv.x + xrv.x; e0 = e0 > 0.f ? e0 : SLOPE * e0;
        float e1 = xlv.y + xrv.y; e1 = e1 > 0.f ? e1 : SLOPE * e1;
        float v = e0 * atv.x + e1 * atv.y;
        v += __shfl_xor(v, 1);
        v += __shfl_xor(v, 2);
        v += __shfl_xor(v, 4);
        v += __shfl_xor(v, 8);        // all 16 lanes of the head hold the logit
        const float a = __expf(v);
        z += a;
        acc.x += a * xlv.x;
        acc.y += a * xlv.y;
    }
    const float inv = 1.f / z;
    const float ox = acc.x * inv, oy = acc.y * inv;

    // LayerNorm across the wave (full 128-dim row lives in the 64 lanes)
    float s1 = ox + oy, s2 = ox * ox + oy * oy;
#pragma unroll
    for (int off = 1; off < 64; off <<= 1) {
        s1 += __shfl_xor(s1, off);
        s2 += __shfl_xor(s2, off);
    }
    const float mu = s1 / (float)HID;
    const float rstd = rsqrtf(s2 / (float)HID - mu * mu + LN_EPS);
    float nx = (ox - mu) * rstd * g[lane * 2]     + b[lane * 2];
    float ny = (oy - mu) * rstd * g[lane * 2 + 1] + b[lane * 2 + 1];
    nx = nx > 0.f ? nx : expm1f(nx);   // ELU
    ny = ny > 0.f ? ny : expm1f(ny);
    const float2 hv = *(const float2*)(hres + (size_t)node * HID + lane * 2);
    float2 res; res.x = hv.x + nx; res.y = hv.y + ny;
    *(float2*)(dest + (size_t)node * HID + lane * 2) = res;
}

extern "C" void kernel_launch(void* const* d_in, const int* in_sizes, int n_in,
                              void* d_out, int out_size, void* d_ws, size_t ws_size,
                              hipStream_t stream) {
    const float* x       = (const float*)d_in[0];
    const float* W_in    = (const float*)d_in[1];
    const float* b_in    = (const float*)d_in[2];
    const float* ln_in_g = (const float*)d_in[3];
    const float* ln_in_b = (const float*)d_in[4];
    const float* Wl      = (const float*)d_in[5];
    const float* Wr      = (const float*)d_in[6];
    const float* att     = (const float*)d_in[7];
    const float* ln_g    = (const float*)d_in[8];
    const float* ln_b    = (const float*)d_in[9];
    const int*   ei      = (const int*)d_in[10];
    float* out = (float*)d_out;

    // workspace: h, xl, xr (floats) then cnt, fill, rowptr, esrc (ints)
    float* h  = (float*)d_ws;
    float* xl = h  + (size_t)NN * HID;
    float* xr = xl + (size_t)NN * HID;
    int* cnt    = (int*)(xr + (size_t)NN * HID);
    int* fill   = cnt + NN;
    int* rowptr = fill + NN;
    int* esrc   = rowptr + (NN + 1);

    // ---- CSR build (edge structure is layer-invariant) ----
    hipMemsetAsync(cnt, 0, 2 * NN * sizeof(int), stream);   // cnt + fill
    const int eblocks = (EP + 255) / 256;
    dst_hist<<<eblocks, 256, 0, stream>>>(ei, cnt);
    scan_rowptr<<<1, 1024, 0, stream>>>(cnt, rowptr);
    csr_scatter<<<eblocks, 256, 0, stream>>>(ei, rowptr, fill, esrc);

    gemm_in_ln_relu<<<NN / 8, 128, 0, stream>>>(x, W_in, b_in, ln_in_g, ln_in_b, h);

    for (int l = 0; l < 2; l++) {
        gemm_xlxr<<<NN / 8, 128, 0, stream>>>(h, Wl + (size_t)l * HID * HID,
                                              Wr + (size_t)l * HID * HID, xl, xr);
        gat_ln<<<(NN + 3) / 4, 256, 0, stream>>>(xl, xr, att + (size_t)l * HID,
                                                 rowptr, esrc,
                                                 ln_g + (size_t)l * HID,
                                                 ln_b + (size_t)l * HID,
                                                 h, (l == 0) ? h : out);
    }
}